// Round 3
// baseline (191.192 us; speedup 1.0000x reference)
//
#include <hip/hip_runtime.h>

// Problem constants
#define B_TOT   65536
#define IN_DIM  512
#define H0      256
#define H1      128
#define HH      64
#define NDIS    12

typedef __bf16 bf16_t;
typedef __bf16 bf16x4 __attribute__((ext_vector_type(4)));
typedef __bf16 bf16x8 __attribute__((ext_vector_type(8)));
typedef float  f32x4  __attribute__((ext_vector_type(4)));
typedef float  floatx4 __attribute__((ext_vector_type(4)));

// ---- workspace layout (bytes) ----
#define WS_W0T   0u          // bf16 [256][512]  (W0t[c][k] = W0[k][c])
#define WS_W1T   262144u     // bf16 [128][256]
#define WS_WZT   327680u     // bf16 [12][64][128] (Wzt[d][h][e] = Wz[d][e][h])
#define WS_WIT   524288u     // bf16 [16][128]  (w_init rows, zero-padded to 16)
#define WS_AL0   528384u     // f32 [256]
#define WS_BE0   529408u     // f32 [256]
#define WS_AL1   530432u     // f32 [128]
#define WS_BE1   530944u     // f32 [128]
#define WS_NEED  531456u

// ---- fused-kernel LDS layout (bytes) ----
// P0: xs dbuf [2][64][136] bf16          [0..34816)
// P1/P2: hs [64][264] bf16 @0            [0..33792)   (aliases xs, after GEMM0)
// P3/P4: ps [64][17] f32 @0              [0..4352)    (aliases hs, after GEMM1)
// P2..P4: zs [64][136] bf16 @34816       [34816..52224)
#define L_XS0    0u
#define L_XS1    17408u
#define L_HS     0u
#define L_PS     0u
#define L_ZS     34816u
#define L_TOTAL  52224u

// =====================================================================
// Prep: transpose + f32->bf16 weights, fold BN (+linear bias) into alpha/beta
// =====================================================================
__global__ void prep_kernel(const float* __restrict__ W0, const float* __restrict__ b0,
                            const float* __restrict__ g0, const float* __restrict__ bb0,
                            const float* __restrict__ mm0, const float* __restrict__ vv0,
                            const float* __restrict__ W1, const float* __restrict__ b1,
                            const float* __restrict__ g1, const float* __restrict__ bb1,
                            const float* __restrict__ mm1, const float* __restrict__ vv1,
                            const float* __restrict__ w_init, const float* __restrict__ Wz,
                            char* __restrict__ ws)
{
    bf16_t* W0t = (bf16_t*)(ws + WS_W0T);
    bf16_t* W1t = (bf16_t*)(ws + WS_W1T);
    bf16_t* Wzt = (bf16_t*)(ws + WS_WZT);
    bf16_t* wiT = (bf16_t*)(ws + WS_WIT);
    float* al0 = (float*)(ws + WS_AL0);
    float* be0 = (float*)(ws + WS_BE0);
    float* al1 = (float*)(ws + WS_AL1);
    float* be1 = (float*)(ws + WS_BE1);

    int t = blockIdx.x * 256 + threadIdx.x;   // 512*256 = 131072 threads

    { // W0t: 256*512 (one elem per thread)
        int c = t >> 9, k = t & 511;
        W0t[t] = (bf16_t)W0[k * H0 + c];
    }
    if (t < H1 * H0) { // W1t
        int c = t >> 8, k = t & 255;
        W1t[t] = (bf16_t)W1[k * H1 + c];
    }
    if (t < NDIS * HH * H1) { // Wzt ; Wz is [12][128][64]
        int d = t >> 13, r = t & 8191, h = r >> 7, e = r & 127;
        Wzt[t] = (bf16_t)Wz[d * 8192 + e * 64 + h];
    }
    if (t < 16 * H1) { // w_initT (pad 12->16)
        int d = t >> 7, e = t & 127;
        wiT[t] = (d < NDIS) ? (bf16_t)w_init[d * H1 + e] : (bf16_t)0.0f;
    }
    if (t < H0) {
        float a = g0[t] * rsqrtf(vv0[t] + 1e-5f);
        al0[t] = a;
        be0[t] = (b0[t] - mm0[t]) * a + bb0[t];
    }
    if (t < H1) {
        float a = g1[t] * rsqrtf(vv1[t] + 1e-5f);
        al1[t] = a;
        be1[t] = (b1[t] - mm1[t]) * a + bb1[t];
    }
}

// =====================================================================
// Fused kernel: 64 rows per block, end-to-end (encoder + heads).
// 512 threads = 8 waves. Only x is LDS-staged; all weights direct from L2.
// =====================================================================
__global__ __launch_bounds__(512, 4) void fused_kernel(
    const float* __restrict__ x,
    const bf16_t* __restrict__ W0t, const bf16_t* __restrict__ W1t,
    const float* __restrict__ al0, const float* __restrict__ be0,
    const float* __restrict__ al1, const float* __restrict__ be1,
    const bf16_t* __restrict__ Wzt, const bf16_t* __restrict__ wiT,
    const float* __restrict__ b_init, const float* __restrict__ Wp,
    const float* __restrict__ bh, const float* __restrict__ Wo,
    const float* __restrict__ bo, const float* __restrict__ pred_w,
    const int* __restrict__ pred_idx, float* __restrict__ out)
{
    __shared__ __align__(16) char smem[L_TOTAL];

    const int tid  = threadIdx.x;
    const int lane = tid & 63, wid = tid >> 6;
    const int l15 = lane & 15, lg = lane >> 4;
    const int m0 = blockIdx.x * 64;

    bf16_t* xsb[2] = { (bf16_t*)(smem + L_XS0), (bf16_t*)(smem + L_XS1) };

    // ---------------- P0: GEMM0 (64x512x256), BK=128, x double-buffered ----
    const int wr = wid >> 2, wc = wid & 3;
    const int xrow0 = tid >> 5;                 // 0..15 (4 row-blocks of 16)
    const int xc    = (tid & 31) << 2;          // f32 col 0..124
    const float* xg = x + (m0 + xrow0) * IN_DIM + xc;

#define XLOAD(v, ks) { _Pragma("unroll") \
    for (int i = 0; i < 4; ++i) v[i] = *(const floatx4*)(xg + i * 16 * IN_DIM + (ks) * 128); }
#define XSTORE(v, bi) { _Pragma("unroll") \
    for (int i = 0; i < 4; ++i) { bf16x4 o; \
        o[0] = (bf16_t)v[i][0]; o[1] = (bf16_t)v[i][1]; \
        o[2] = (bf16_t)v[i][2]; o[3] = (bf16_t)v[i][3]; \
        *(bf16x4*)(xsb[bi] + (xrow0 + 16 * i) * 136 + xc) = o; } }

    f32x4 acc[2][4] = {};

    {
        floatx4 v[4];
        XLOAD(v, 0);
        XSTORE(v, 0);
    }
    __syncthreads();

    #pragma unroll
    for (int ks = 0; ks < 4; ++ks) {
        floatx4 v[4];
        if (ks < 3) XLOAD(v, ks + 1);          // issue next-tile loads first
        // MFMA on buffer ks&1, B direct from W0t (L2-resident)
        #pragma unroll
        for (int kf = 0; kf < 4; ++kf) {
            bf16x8 a[2], b[4];
            #pragma unroll
            for (int mr = 0; mr < 2; ++mr)
                a[mr] = *(const bf16x8*)(xsb[ks & 1] + (wr * 32 + mr * 16 + l15) * 136 + kf * 32 + lg * 8);
            #pragma unroll
            for (int nr = 0; nr < 4; ++nr)
                b[nr] = *(const bf16x8*)(W0t + (wc * 64 + nr * 16 + l15) * IN_DIM + ks * 128 + kf * 32 + lg * 8);
            #pragma unroll
            for (int mr = 0; mr < 2; ++mr)
                #pragma unroll
                for (int nr = 0; nr < 4; ++nr)
                    acc[mr][nr] = __builtin_amdgcn_mfma_f32_16x16x32_bf16(a[mr], b[nr], acc[mr][nr], 0, 0, 0);
        }
        if (ks < 3) XSTORE(v, (ks + 1) & 1);
        __syncthreads();
    }

    // ---------------- P1: BN0 + ReLU -> hs (aliases xs) ----------------
    {
        bf16_t* hs = (bf16_t*)(smem + L_HS);
        #pragma unroll
        for (int mr = 0; mr < 2; ++mr)
            #pragma unroll
            for (int nr = 0; nr < 4; ++nr) {
                int c = wc * 64 + nr * 16 + l15;
                float alpha = al0[c], beta = be0[c];
                #pragma unroll
                for (int j = 0; j < 4; ++j) {
                    int r = wr * 32 + mr * 16 + lg * 4 + j;
                    float v = fmaxf(acc[mr][nr][j] * alpha + beta, 0.0f);
                    hs[r * 264 + c] = (bf16_t)v;
                }
            }
    }
    __syncthreads();

    // ---------------- P2: GEMM1 (64x256x128), A from hs, B direct L2 -------
    {
        bf16_t* hs = (bf16_t*)(smem + L_HS);
        bf16_t* zs = (bf16_t*)(smem + L_ZS);
        f32x4 acc2[2][2] = {};
        #pragma unroll
        for (int kf = 0; kf < 8; ++kf) {
            bf16x8 a[2], b[2];
            #pragma unroll
            for (int mr = 0; mr < 2; ++mr)
                a[mr] = *(const bf16x8*)(hs + (wr * 32 + mr * 16 + l15) * 264 + kf * 32 + lg * 8);
            #pragma unroll
            for (int nr = 0; nr < 2; ++nr)
                b[nr] = *(const bf16x8*)(W1t + (wc * 32 + nr * 16 + l15) * H0 + kf * 32 + lg * 8);
            #pragma unroll
            for (int mr = 0; mr < 2; ++mr)
                #pragma unroll
                for (int nr = 0; nr < 2; ++nr)
                    acc2[mr][nr] = __builtin_amdgcn_mfma_f32_16x16x32_bf16(a[mr], b[nr], acc2[mr][nr], 0, 0, 0);
        }
        // BN1 + ReLU -> zs (bf16)
        #pragma unroll
        for (int mr = 0; mr < 2; ++mr)
            #pragma unroll
            for (int nr = 0; nr < 2; ++nr) {
                int c = wc * 32 + nr * 16 + l15;
                float alpha = al1[c], beta = be1[c];
                #pragma unroll
                for (int j = 0; j < 4; ++j) {
                    int r = wr * 32 + mr * 16 + lg * 4 + j;
                    float v = fmaxf(acc2[mr][nr][j] * alpha + beta, 0.0f);
                    zs[r * 136 + c] = (bf16_t)v;
                }
            }
    }
    __syncthreads();

    // ---------------- P3: p = sigmoid(z @ w_init^T), B direct from L2 ------
    {
        bf16_t* zs = (bf16_t*)(smem + L_ZS);
        float*  ps = (float*)(smem + L_PS);
        if (wid < 4) {
            f32x4 pacc = {};
            #pragma unroll
            for (int kf = 0; kf < 4; ++kf) {
                bf16x8 a = *(const bf16x8*)(zs + (wid * 16 + l15) * 136 + kf * 32 + lg * 8);
                bf16x8 b = *(const bf16x8*)(wiT + l15 * H1 + kf * 32 + lg * 8);
                pacc = __builtin_amdgcn_mfma_f32_16x16x32_bf16(a, b, pacc, 0, 0, 0);
            }
            int d = l15;
            float bi = (d < NDIS) ? b_init[d] : 0.0f;
            #pragma unroll
            for (int j = 0; j < 4; ++j) {
                int r = wid * 16 + lg * 4 + j;
                ps[r * 17 + d] = 1.0f / (1.0f + __expf(-(pacc[j] + bi)));
            }
        }
    }
    __syncthreads();

    // ---------------- P4: 12 heads, barrier-free, Wz direct from L2 --------
    {
        bf16_t* zs = (bf16_t*)(smem + L_ZS);
        float*  ps = (float*)(smem + L_PS);
        const int g  = wid >> 2;          // waves 0-3 -> d 0..5, waves 4-7 -> d 6..11
        const int mt = wid & 3;           // 16-row M-tile

        for (int i = 0; i < 6; ++i) {
            int d = g * 6 + i;

            f32x4 hacc[4] = {};
            #pragma unroll
            for (int kf = 0; kf < 4; ++kf) {
                bf16x8 a = *(const bf16x8*)(zs + (mt * 16 + l15) * 136 + kf * 32 + lg * 8);
                #pragma unroll
                for (int nr = 0; nr < 4; ++nr) {
                    bf16x8 b = *(const bf16x8*)(Wzt + d * 8192 + (nr * 16 + l15) * H1 + kf * 32 + lg * 8);
                    hacc[nr] = __builtin_amdgcn_mfma_f32_16x16x32_bf16(a, b, hacc[nr], 0, 0, 0);
                }
            }

            // epilogue: + aug@Wp + bh, ReLU, dot Wo, sigmoid
            int i0 = pred_idx[d * 3 + 0], i1 = pred_idx[d * 3 + 1], i2 = pred_idx[d * 3 + 2];
            float w0p = pred_w[d * 3 + 0], w1p = pred_w[d * 3 + 1], w2p = pred_w[d * 3 + 2];
            float bod = bo[d];

            float aug0[4], aug1[4], aug2[4];
            #pragma unroll
            for (int j = 0; j < 4; ++j) {
                int r = mt * 16 + lg * 4 + j;
                aug0[j] = ps[r * 17 + i0] * w0p;
                aug1[j] = ps[r * 17 + i1] * w1p;
                aug2[j] = ps[r * 17 + i2] * w2p;
            }
            float res[4] = {0.f, 0.f, 0.f, 0.f};
            #pragma unroll
            for (int nr = 0; nr < 4; ++nr) {
                int c = nr * 16 + l15;
                float bhv = bh[d * 64 + c];
                float wpa = Wp[d * 192 + c], wpb = Wp[d * 192 + 64 + c], wpc = Wp[d * 192 + 128 + c];
                float wov = Wo[d * 64 + c];
                #pragma unroll
                for (int j = 0; j < 4; ++j) {
                    float v = hacc[nr][j] + bhv + aug0[j] * wpa + aug1[j] * wpb + aug2[j] * wpc;
                    res[j] += fmaxf(v, 0.0f) * wov;
                }
            }
            #pragma unroll
            for (int j = 0; j < 4; ++j) {
                float s = res[j];
                s += __shfl_xor(s, 1); s += __shfl_xor(s, 2);
                s += __shfl_xor(s, 4); s += __shfl_xor(s, 8);
                if (l15 == 0) {
                    int r = mt * 16 + lg * 4 + j;
                    out[(m0 + r) * NDIS + d] = 1.0f / (1.0f + __expf(-(s + bod)));
                }
            }
        }
    }
}

// =====================================================================
extern "C" void kernel_launch(void* const* d_in, const int* in_sizes, int n_in,
                              void* d_out, int out_size, void* d_ws, size_t ws_size,
                              hipStream_t stream) {
    if (ws_size < (size_t)WS_NEED) return;

    const float* x      = (const float*)d_in[0];
    const float* W0     = (const float*)d_in[1];
    const float* b0     = (const float*)d_in[2];
    const float* g0     = (const float*)d_in[3];
    const float* bb0    = (const float*)d_in[4];
    const float* mm0    = (const float*)d_in[5];
    const float* vv0    = (const float*)d_in[6];
    const float* W1     = (const float*)d_in[7];
    const float* b1     = (const float*)d_in[8];
    const float* g1     = (const float*)d_in[9];
    const float* bb1    = (const float*)d_in[10];
    const float* mm1    = (const float*)d_in[11];
    const float* vv1    = (const float*)d_in[12];
    const float* w_init = (const float*)d_in[13];
    const float* b_init = (const float*)d_in[14];
    const float* Wz     = (const float*)d_in[15];
    const float* Wp     = (const float*)d_in[16];
    const float* bh     = (const float*)d_in[17];
    const float* Wo     = (const float*)d_in[18];
    const float* bo     = (const float*)d_in[19];
    const float* pred_w = (const float*)d_in[20];
    const int*   pred_idx = (const int*)d_in[21];

    char* ws = (char*)d_ws;
    const bf16_t* W0t = (const bf16_t*)(ws + WS_W0T);
    const bf16_t* W1t = (const bf16_t*)(ws + WS_W1T);
    const bf16_t* Wzt = (const bf16_t*)(ws + WS_WZT);
    const bf16_t* wiT = (const bf16_t*)(ws + WS_WIT);
    const float* al0 = (const float*)(ws + WS_AL0);
    const float* be0 = (const float*)(ws + WS_BE0);
    const float* al1 = (const float*)(ws + WS_AL1);
    const float* be1 = (const float*)(ws + WS_BE1);

    prep_kernel<<<dim3(512), dim3(256), 0, stream>>>(
        W0, b0, g0, bb0, mm0, vv0, W1, b1, g1, bb1, mm1, vv1, w_init, Wz, ws);

    fused_kernel<<<dim3(B_TOT / 64), dim3(512), 0, stream>>>(
        x, W0t, W1t, al0, be0, al1, be1, Wzt, wiT, b_init, Wp, bh, Wo, bo,
        pred_w, pred_idx, (float*)d_out);
}

// Round 4
// 135.453 us; speedup vs baseline: 1.4115x; 1.4115x over previous
//
#include <hip/hip_runtime.h>

// Problem constants
#define B_TOT   65536
#define IN_DIM  512
#define H0      256
#define H1      128
#define HH      64
#define NDIS    12

typedef __bf16 bf16_t;
typedef __bf16 bf16x4 __attribute__((ext_vector_type(4)));
typedef __bf16 bf16x8 __attribute__((ext_vector_type(8)));
typedef float  f32x4  __attribute__((ext_vector_type(4)));
typedef float  floatx4 __attribute__((ext_vector_type(4)));

// ---- workspace layout (bytes) ----
#define WS_W0T   0u          // bf16 [256][512]  (W0t[c][k] = W0[k][c])
#define WS_W1T   262144u     // bf16 [128][256]
#define WS_WZT   327680u     // bf16 [12][64][128] (Wzt[d][h][e] = Wz[d][e][h])
#define WS_WIT   524288u     // bf16 [16][128]  (w_init rows, zero-padded to 16)
#define WS_AL0   528384u     // f32 [256]
#define WS_BE0   529408u     // f32 [256]
#define WS_AL1   530432u     // f32 [128]
#define WS_BE1   530944u     // f32 [128]
#define WS_NEED  531456u

// ---- fused-kernel LDS layout (bytes) ----
// P0: xs dbuf 2x[64][72] bf16 @0                     [0..18432)
// P1/P2: hs [64][264] bf16 @0 (aliases xs)           [0..33792)
// P4: wzs [2 groups][64][136] bf16 @0 (aliases hs)   [0..34816)
// P2..P4: zs [64][136] bf16 @34816                   [34816..52224)
// P3/P4: ps [64][17] f32 @52224                      [52224..56576)
#define L_ZS     34816u
#define L_PS     52224u
#define L_TOTAL  56576u

// =====================================================================
// Prep: transpose + f32->bf16 weights, fold BN (+linear bias) into alpha/beta
// =====================================================================
__global__ void prep_kernel(const float* __restrict__ W0, const float* __restrict__ b0,
                            const float* __restrict__ g0, const float* __restrict__ bb0,
                            const float* __restrict__ mm0, const float* __restrict__ vv0,
                            const float* __restrict__ W1, const float* __restrict__ b1,
                            const float* __restrict__ g1, const float* __restrict__ bb1,
                            const float* __restrict__ mm1, const float* __restrict__ vv1,
                            const float* __restrict__ w_init, const float* __restrict__ Wz,
                            char* __restrict__ ws)
{
    bf16_t* W0t = (bf16_t*)(ws + WS_W0T);
    bf16_t* W1t = (bf16_t*)(ws + WS_W1T);
    bf16_t* Wzt = (bf16_t*)(ws + WS_WZT);
    bf16_t* wiT = (bf16_t*)(ws + WS_WIT);
    float* al0 = (float*)(ws + WS_AL0);
    float* be0 = (float*)(ws + WS_BE0);
    float* al1 = (float*)(ws + WS_AL1);
    float* be1 = (float*)(ws + WS_BE1);

    int t = blockIdx.x * 256 + threadIdx.x;   // 512*256 = 131072 threads

    { // W0t: 256*512 (one elem per thread)
        int c = t >> 9, k = t & 511;
        W0t[t] = (bf16_t)W0[k * H0 + c];
    }
    if (t < H1 * H0) { // W1t
        int c = t >> 8, k = t & 255;
        W1t[t] = (bf16_t)W1[k * H1 + c];
    }
    if (t < NDIS * HH * H1) { // Wzt ; Wz is [12][128][64]
        int d = t >> 13, r = t & 8191, h = r >> 7, e = r & 127;
        Wzt[t] = (bf16_t)Wz[d * 8192 + e * 64 + h];
    }
    if (t < 16 * H1) { // w_initT (pad 12->16)
        int d = t >> 7, e = t & 127;
        wiT[t] = (d < NDIS) ? (bf16_t)w_init[d * H1 + e] : (bf16_t)0.0f;
    }
    if (t < H0) {
        float a = g0[t] * rsqrtf(vv0[t] + 1e-5f);
        al0[t] = a;
        be0[t] = (b0[t] - mm0[t]) * a + bb0[t];
    }
    if (t < H1) {
        float a = g1[t] * rsqrtf(vv1[t] + 1e-5f);
        al1[t] = a;
        be1[t] = (b1[t] - mm1[t]) * a + bb1[t];
    }
}

// =====================================================================
// Fused kernel: 64 rows per block, end-to-end. 512 threads = 8 waves.
// All global loads are register-prefetched ahead of use (T14 pattern).
// =====================================================================
__global__ __launch_bounds__(512, 4) void fused_kernel(
    const float* __restrict__ x,
    const bf16_t* __restrict__ W0t, const bf16_t* __restrict__ W1t,
    const float* __restrict__ al0, const float* __restrict__ be0,
    const float* __restrict__ al1, const float* __restrict__ be1,
    const bf16_t* __restrict__ Wzt, const bf16_t* __restrict__ wiT,
    const float* __restrict__ b_init, const float* __restrict__ Wp,
    const float* __restrict__ bh, const float* __restrict__ Wo,
    const float* __restrict__ bo, const float* __restrict__ pred_w,
    const int* __restrict__ pred_idx, float* __restrict__ out)
{
    __shared__ __align__(16) char smem[L_TOTAL];

    const int tid  = threadIdx.x;
    const int lane = tid & 63, wid = tid >> 6;
    const int l15 = lane & 15, lg = lane >> 4;
    const int m0 = blockIdx.x * 64;
    const int wr = wid >> 2, wc = wid & 3;

    // ---------------- P0: GEMM0 (64x512x256), BK=64, 8 steps -------------
    // x: fully prefetched to regs (2 batches of 8 float4). W0: L2->regs,
    // issued a half/full step ahead. xs double-buffered; 1 barrier/step.
    const float* xg = x + (m0 + (tid >> 3)) * IN_DIM + ((tid & 7) << 3);
    bf16_t* xst = (bf16_t*)smem + (tid >> 3) * 72 + ((tid & 7) << 3);
    const bf16_t* wg = W0t + (wc * 64 + l15) * IN_DIM + lg * 8;

    floatx4 xv[16];
    #pragma unroll
    for (int i = 0; i < 8; ++i) xv[i] = *(const floatx4*)(xg + (i >> 1) * 64 + (i & 1) * 4);

    bf16x8 wb0[4], wb1[4];
    #pragma unroll
    for (int nr = 0; nr < 4; ++nr) wb0[nr] = *(const bf16x8*)(wg + nr * 8192);

#define STORE_X(s) { bf16x8 o; \
    o[0]=(bf16_t)xv[2*(s)][0];   o[1]=(bf16_t)xv[2*(s)][1]; \
    o[2]=(bf16_t)xv[2*(s)][2];   o[3]=(bf16_t)xv[2*(s)][3]; \
    o[4]=(bf16_t)xv[2*(s)+1][0]; o[5]=(bf16_t)xv[2*(s)+1][1]; \
    o[6]=(bf16_t)xv[2*(s)+1][2]; o[7]=(bf16_t)xv[2*(s)+1][3]; \
    *(bf16x8*)(xst + ((s)&1) * 4608) = o; }

    f32x4 acc[2][4] = {};

    STORE_X(0);
    __syncthreads();

    #pragma unroll
    for (int ks = 0; ks < 8; ++ks) {
        const bf16_t* xsrd = (bf16_t*)smem + (ks & 1) * 4608;
        // issue kf=1 frags of this step
        #pragma unroll
        for (int nr = 0; nr < 4; ++nr)
            wb1[nr] = *(const bf16x8*)(wg + nr * 8192 + ks * 64 + 32);
        // MFMA kf=0
        {
            bf16x8 a[2];
            #pragma unroll
            for (int mr = 0; mr < 2; ++mr)
                a[mr] = *(const bf16x8*)(xsrd + (wr * 32 + mr * 16 + l15) * 72 + lg * 8);
            #pragma unroll
            for (int mr = 0; mr < 2; ++mr)
                #pragma unroll
                for (int nr = 0; nr < 4; ++nr)
                    acc[mr][nr] = __builtin_amdgcn_mfma_f32_16x16x32_bf16(a[mr], wb0[nr], acc[mr][nr], 0, 0, 0);
        }
        // issue kf=0 frags of next step
        if (ks < 7) {
            #pragma unroll
            for (int nr = 0; nr < 4; ++nr)
                wb0[nr] = *(const bf16x8*)(wg + nr * 8192 + (ks + 1) * 64);
        }
        // second x batch
        if (ks == 2) {
            #pragma unroll
            for (int i = 8; i < 16; ++i)
                xv[i] = *(const floatx4*)(xg + (i >> 1) * 64 + (i & 1) * 4);
        }
        // MFMA kf=1
        {
            bf16x8 a[2];
            #pragma unroll
            for (int mr = 0; mr < 2; ++mr)
                a[mr] = *(const bf16x8*)(xsrd + (wr * 32 + mr * 16 + l15) * 72 + 32 + lg * 8);
            #pragma unroll
            for (int mr = 0; mr < 2; ++mr)
                #pragma unroll
                for (int nr = 0; nr < 4; ++nr)
                    acc[mr][nr] = __builtin_amdgcn_mfma_f32_16x16x32_bf16(a[mr], wb1[nr], acc[mr][nr], 0, 0, 0);
        }
        // stage next x tile into the other buffer
        switch (ks) {
            case 0: STORE_X(1); break;
            case 1: STORE_X(2); break;
            case 2: STORE_X(3); break;
            case 3: STORE_X(4); break;
            case 4: STORE_X(5); break;
            case 5: STORE_X(6); break;
            case 6: STORE_X(7); break;
            default: break;
        }
        __syncthreads();
    }

    // ---------------- P1: BN0 + ReLU -> hs (aliases xs) ----------------
    {
        bf16_t* hs = (bf16_t*)smem;
        #pragma unroll
        for (int mr = 0; mr < 2; ++mr)
            #pragma unroll
            for (int nr = 0; nr < 4; ++nr) {
                int c = wc * 64 + nr * 16 + l15;
                float alpha = al0[c], beta = be0[c];
                #pragma unroll
                for (int j = 0; j < 4; ++j) {
                    int r = wr * 32 + mr * 16 + lg * 4 + j;
                    float v = fmaxf(acc[mr][nr][j] * alpha + beta, 0.0f);
                    hs[r * 264 + c] = (bf16_t)v;
                }
            }
    }
    __syncthreads();

    // ---------------- P2: GEMM1 (64x256x128), A from hs, B from L2 w/ prefetch
    {
        bf16_t* hs = (bf16_t*)smem;
        bf16_t* zs = (bf16_t*)(smem + L_ZS);
        const bf16_t* w1g = W1t + (wc * 32 + l15) * H0 + lg * 8;
        f32x4 acc2[2][2] = {};
        bf16x8 bb[2][2];
        #pragma unroll
        for (int nr = 0; nr < 2; ++nr) bb[0][nr] = *(const bf16x8*)(w1g + nr * 4096);
        #pragma unroll
        for (int kf = 0; kf < 8; ++kf) {
            if (kf < 7) {
                #pragma unroll
                for (int nr = 0; nr < 2; ++nr)
                    bb[(kf + 1) & 1][nr] = *(const bf16x8*)(w1g + nr * 4096 + (kf + 1) * 32);
            }
            bf16x8 a[2];
            #pragma unroll
            for (int mr = 0; mr < 2; ++mr)
                a[mr] = *(const bf16x8*)(hs + (wr * 32 + mr * 16 + l15) * 264 + kf * 32 + lg * 8);
            #pragma unroll
            for (int mr = 0; mr < 2; ++mr)
                #pragma unroll
                for (int nr = 0; nr < 2; ++nr)
                    acc2[mr][nr] = __builtin_amdgcn_mfma_f32_16x16x32_bf16(a[mr], bb[kf & 1][nr], acc2[mr][nr], 0, 0, 0);
        }
        // BN1 + ReLU -> zs
        #pragma unroll
        for (int mr = 0; mr < 2; ++mr)
            #pragma unroll
            for (int nr = 0; nr < 2; ++nr) {
                int c = wc * 32 + nr * 16 + l15;
                float alpha = al1[c], beta = be1[c];
                #pragma unroll
                for (int j = 0; j < 4; ++j) {
                    int r = wr * 32 + mr * 16 + lg * 4 + j;
                    float v = fmaxf(acc2[mr][nr][j] * alpha + beta, 0.0f);
                    zs[r * 136 + c] = (bf16_t)v;
                }
            }
    }
    __syncthreads();

    // ---------------- P3 + P4 prologue ----------------
    const int g  = wid >> 2;          // waves 0-3 -> d 0..5, waves 4-7 -> d 6..11
    const int mt = wid & 3;           // 16-row M-tile
    const int lt = tid & 255;
    bf16_t* wzbuf = (bf16_t*)smem + g * 8704;                 // [64][136] per group
    const bf16_t* wzg = Wzt + (lt >> 2) * 128 + (lt & 3) * 32;
    bf16_t* wzst = wzbuf + (lt >> 2) * 136 + (lt & 3) * 32;

    bf16x8 stg[4];
    // issue loads for this group's first d (covers P3 compute latency)
    #pragma unroll
    for (int c = 0; c < 4; ++c)
        stg[c] = *(const bf16x8*)(wzg + (g * 6) * 8192 + c * 8);

    // P3: p = sigmoid(z @ w_init^T) (waves 0-3 only)
    {
        bf16_t* zs = (bf16_t*)(smem + L_ZS);
        float*  ps = (float*)(smem + L_PS);
        if (wid < 4) {
            f32x4 pacc = {};
            #pragma unroll
            for (int kf = 0; kf < 4; ++kf) {
                bf16x8 a = *(const bf16x8*)(zs + (wid * 16 + l15) * 136 + kf * 32 + lg * 8);
                bf16x8 b = *(const bf16x8*)(wiT + l15 * H1 + kf * 32 + lg * 8);
                pacc = __builtin_amdgcn_mfma_f32_16x16x32_bf16(a, b, pacc, 0, 0, 0);
            }
            int d = l15;
            float bi = (d < NDIS) ? b_init[d] : 0.0f;
            #pragma unroll
            for (int j = 0; j < 4; ++j) {
                int r = wid * 16 + lg * 4 + j;
                ps[r * 17 + d] = 1.0f / (1.0f + __expf(-(pacc[j] + bi)));
            }
        }
    }
    // write first Wz tile (region aliases hs, which is dead after P2 barrier)
    #pragma unroll
    for (int c = 0; c < 4; ++c)
        *(bf16x8*)(wzst + c * 8) = stg[c];
    __syncthreads();

    // ---------------- P4: 12 heads, 2 groups x 6 iters ----------------
    {
        bf16_t* zs = (bf16_t*)(smem + L_ZS);
        float*  ps = (float*)(smem + L_PS);

        for (int i = 0; i < 6; ++i) {
            int d = g * 6 + i;
            // issue next d's loads (used ~a full compute phase later)
            if (i < 5) {
                #pragma unroll
                for (int c = 0; c < 4; ++c)
                    stg[c] = *(const bf16x8*)(wzg + (d + 1) * 8192 + c * 8);
            }

            f32x4 hacc[4] = {};
            #pragma unroll
            for (int kf = 0; kf < 4; ++kf) {
                bf16x8 a = *(const bf16x8*)(zs + (mt * 16 + l15) * 136 + kf * 32 + lg * 8);
                #pragma unroll
                for (int nr = 0; nr < 4; ++nr) {
                    bf16x8 b = *(const bf16x8*)(wzbuf + (nr * 16 + l15) * 136 + kf * 32 + lg * 8);
                    hacc[nr] = __builtin_amdgcn_mfma_f32_16x16x32_bf16(a, b, hacc[nr], 0, 0, 0);
                }
            }

            // epilogue: + aug@Wp + bh, ReLU, dot Wo, sigmoid
            int i0 = pred_idx[d * 3 + 0], i1 = pred_idx[d * 3 + 1], i2 = pred_idx[d * 3 + 2];
            float w0p = pred_w[d * 3 + 0], w1p = pred_w[d * 3 + 1], w2p = pred_w[d * 3 + 2];
            float bod = bo[d];

            float aug0[4], aug1[4], aug2[4];
            #pragma unroll
            for (int j = 0; j < 4; ++j) {
                int r = mt * 16 + lg * 4 + j;
                aug0[j] = ps[r * 17 + i0] * w0p;
                aug1[j] = ps[r * 17 + i1] * w1p;
                aug2[j] = ps[r * 17 + i2] * w2p;
            }
            float res[4] = {0.f, 0.f, 0.f, 0.f};
            #pragma unroll
            for (int nr = 0; nr < 4; ++nr) {
                int c = nr * 16 + l15;
                float bhv = bh[d * 64 + c];
                float wpa = Wp[d * 192 + c], wpb = Wp[d * 192 + 64 + c], wpc = Wp[d * 192 + 128 + c];
                float wov = Wo[d * 64 + c];
                #pragma unroll
                for (int j = 0; j < 4; ++j) {
                    float v = hacc[nr][j] + bhv + aug0[j] * wpa + aug1[j] * wpb + aug2[j] * wpc;
                    res[j] += fmaxf(v, 0.0f) * wov;
                }
            }
            #pragma unroll
            for (int j = 0; j < 4; ++j) {
                float s = res[j];
                s += __shfl_xor(s, 1); s += __shfl_xor(s, 2);
                s += __shfl_xor(s, 4); s += __shfl_xor(s, 8);
                if (l15 == 0) {
                    int r = mt * 16 + lg * 4 + j;
                    out[(m0 + r) * NDIS + d] = 1.0f / (1.0f + __expf(-(s + bod)));
                }
            }
            __syncthreads();                     // everyone done reading wzbuf
            if (i < 5) {
                #pragma unroll
                for (int c = 0; c < 4; ++c)
                    *(bf16x8*)(wzst + c * 8) = stg[c];
                __syncthreads();                 // next tile visible
            }
        }
    }
}

// =====================================================================
extern "C" void kernel_launch(void* const* d_in, const int* in_sizes, int n_in,
                              void* d_out, int out_size, void* d_ws, size_t ws_size,
                              hipStream_t stream) {
    if (ws_size < (size_t)WS_NEED) return;

    const float* x      = (const float*)d_in[0];
    const float* W0     = (const float*)d_in[1];
    const float* b0     = (const float*)d_in[2];
    const float* g0     = (const float*)d_in[3];
    const float* bb0    = (const float*)d_in[4];
    const float* mm0    = (const float*)d_in[5];
    const float* vv0    = (const float*)d_in[6];
    const float* W1     = (const float*)d_in[7];
    const float* b1     = (const float*)d_in[8];
    const float* g1     = (const float*)d_in[9];
    const float* bb1    = (const float*)d_in[10];
    const float* mm1    = (const float*)d_in[11];
    const float* vv1    = (const float*)d_in[12];
    const float* w_init = (const float*)d_in[13];
    const float* b_init = (const float*)d_in[14];
    const float* Wz     = (const float*)d_in[15];
    const float* Wp     = (const float*)d_in[16];
    const float* bh     = (const float*)d_in[17];
    const float* Wo     = (const float*)d_in[18];
    const float* bo     = (const float*)d_in[19];
    const float* pred_w = (const float*)d_in[20];
    const int*   pred_idx = (const int*)d_in[21];

    char* ws = (char*)d_ws;
    const bf16_t* W0t = (const bf16_t*)(ws + WS_W0T);
    const bf16_t* W1t = (const bf16_t*)(ws + WS_W1T);
    const bf16_t* Wzt = (const bf16_t*)(ws + WS_WZT);
    const bf16_t* wiT = (const bf16_t*)(ws + WS_WIT);
    const float* al0 = (const float*)(ws + WS_AL0);
    const float* be0 = (const float*)(ws + WS_BE0);
    const float* al1 = (const float*)(ws + WS_AL1);
    const float* be1 = (const float*)(ws + WS_BE1);

    prep_kernel<<<dim3(512), dim3(256), 0, stream>>>(
        W0, b0, g0, bb0, mm0, vv0, W1, b1, g1, bb1, mm1, vv1, w_init, Wz, ws);

    fused_kernel<<<dim3(B_TOT / 64), dim3(512), 0, stream>>>(
        x, W0t, W1t, al0, be0, al1, be1, Wzt, wiT, b_init, Wp, bh, Wo, bo,
        pred_w, pred_idx, (float*)d_out);
}

// Round 5
// 95.057 us; speedup vs baseline: 2.0114x; 1.4250x over previous
//
#include <hip/hip_runtime.h>
#include <stdint.h>

// Problem constants
#define B_TOT   65536
#define IN_DIM  512
#define H0      256
#define H1      128
#define HH      64
#define NDIS    12

typedef __bf16 bf16_t;
typedef __bf16 bf16x8 __attribute__((ext_vector_type(8)));
typedef float  f32x4  __attribute__((ext_vector_type(4)));

// ---- workspace layout (bytes) ----
#define WS_W0T   0u          // bf16 [256][512]  (W0t[c][k] = W0[k][c])
#define WS_W1T   262144u     // bf16 [128][256]
#define WS_WZT   327680u     // bf16 [12][64][128] (Wzt[d][h][e] = Wz[d][e][h])
#define WS_WIT   524288u     // bf16 [16][128]  (w_init rows, zero-padded to 16)
#define WS_AL0   528384u     // f32 [256]
#define WS_BE0   529408u     // f32 [256]
#define WS_AL1   530432u     // f32 [128]
#define WS_BE1   530944u     // f32 [128]
#define WS_NEED  531456u

// ---- fused-kernel LDS (33792 B total; 4 blocks/CU) ----
// P0 : xs dbuf 2 x [64 rows][16 slots of 16B] f32, slot-XOR swizzled   [0..32768)
// P1/2: hs [64][264] bf16                                              [0..33792)
// P3+ : zs [64][136] bf16 @0 ; ps [64][17] f32 @17408 ; part @21760
#define L_PS     17408u
#define L_PART   21760u
#define L_TOTAL  33792u

__device__ __forceinline__ void dma16(const void* g, void* l) {
    __builtin_amdgcn_global_load_lds(
        (const __attribute__((address_space(1))) unsigned*)g,
        (__attribute__((address_space(3))) unsigned*)l, 16, 0, 0);
}

__device__ __forceinline__ f32x4 MF(bf16x8 a, bf16x8 b, f32x4 c) {
    return __builtin_amdgcn_mfma_f32_16x16x32_bf16(a, b, c, 0, 0, 0);
}

// read one bf16x8 A-fragment from the swizzled f32 x-tile
__device__ __forceinline__ bf16x8 xfrag(const float* xb, int row, int sb, int l15) {
    const f32x4 u = *(const f32x4*)(xb + row * 64 + ((( sb    ) ^ l15) << 2));
    const f32x4 v = *(const f32x4*)(xb + row * 64 + (((sb + 1) ^ l15) << 2));
    bf16x8 a;
    a[0]=(bf16_t)u[0]; a[1]=(bf16_t)u[1]; a[2]=(bf16_t)u[2]; a[3]=(bf16_t)u[3];
    a[4]=(bf16_t)v[0]; a[5]=(bf16_t)v[1]; a[6]=(bf16_t)v[2]; a[7]=(bf16_t)v[3];
    return a;
}

// =====================================================================
// Prep: transpose + f32->bf16 weights, fold BN (+bias) into alpha/beta
// =====================================================================
__global__ void prep_kernel(const float* __restrict__ W0, const float* __restrict__ b0,
                            const float* __restrict__ g0, const float* __restrict__ bb0,
                            const float* __restrict__ mm0, const float* __restrict__ vv0,
                            const float* __restrict__ W1, const float* __restrict__ b1,
                            const float* __restrict__ g1, const float* __restrict__ bb1,
                            const float* __restrict__ mm1, const float* __restrict__ vv1,
                            const float* __restrict__ w_init, const float* __restrict__ Wz,
                            char* __restrict__ ws)
{
    bf16_t* W0t = (bf16_t*)(ws + WS_W0T);
    bf16_t* W1t = (bf16_t*)(ws + WS_W1T);
    bf16_t* Wzt = (bf16_t*)(ws + WS_WZT);
    bf16_t* wiT = (bf16_t*)(ws + WS_WIT);
    float* al0 = (float*)(ws + WS_AL0);
    float* be0 = (float*)(ws + WS_BE0);
    float* al1 = (float*)(ws + WS_AL1);
    float* be1 = (float*)(ws + WS_BE1);

    int t = blockIdx.x * 256 + threadIdx.x;   // 512*256 = 131072 threads

    { // W0t: 256*512
        int c = t >> 9, k = t & 511;
        W0t[t] = (bf16_t)W0[k * H0 + c];
    }
    if (t < H1 * H0) { // W1t
        int c = t >> 8, k = t & 255;
        W1t[t] = (bf16_t)W1[k * H1 + c];
    }
    if (t < NDIS * HH * H1) { // Wzt ; Wz is [12][128][64]
        int d = t >> 13, r = t & 8191, h = r >> 7, e = r & 127;
        Wzt[t] = (bf16_t)Wz[d * 8192 + e * 64 + h];
    }
    if (t < 16 * H1) { // w_initT (pad 12->16)
        int d = t >> 7, e = t & 127;
        wiT[t] = (d < NDIS) ? (bf16_t)w_init[d * H1 + e] : (bf16_t)0.0f;
    }
    if (t < H0) {
        float a = g0[t] * rsqrtf(vv0[t] + 1e-5f);
        al0[t] = a;
        be0[t] = (b0[t] - mm0[t]) * a + bb0[t];
    }
    if (t < H1) {
        float a = g1[t] * rsqrtf(vv1[t] + 1e-5f);
        al1[t] = a;
        be1[t] = (b1[t] - mm1[t]) * a + bb1[t];
    }
}

// =====================================================================
// Fused kernel: 64 rows/block, 256 threads (4 waves), 4 blocks/CU.
// =====================================================================
__global__ __launch_bounds__(256, 4) void fused_kernel(
    const float* __restrict__ x,
    const bf16_t* __restrict__ W0t, const bf16_t* __restrict__ W1t,
    const float* __restrict__ al0, const float* __restrict__ be0,
    const float* __restrict__ al1, const float* __restrict__ be1,
    const bf16_t* __restrict__ Wzt, const bf16_t* __restrict__ wiT,
    const float* __restrict__ b_init, const float* __restrict__ Wp,
    const float* __restrict__ bh, const float* __restrict__ Wo,
    const float* __restrict__ bo, const float* __restrict__ pred_w,
    const int* __restrict__ pred_idx, float* __restrict__ out)
{
    __shared__ __align__(16) char smem[L_TOTAL];

    const int tid  = threadIdx.x;
    const int lane = tid & 63, wid = tid >> 6;
    const int l15 = lane & 15, lg = lane >> 4;
    const int m0 = blockIdx.x * 64;

    // ---------------- P0: GEMM0 (64x512x256), BK=64, x via global_load_lds
    // LDS x tile: [row][slot] where slot(16B) = gslot ^ (row&15) (bijective).
    const float* xsrcb[4];
    float* xdstb[4];
    #pragma unroll
    for (int i = 0; i < 4; ++i) {
        int row = wid * 16 + i * 4 + (lane >> 4);
        int gs  = (lane & 15) ^ (row & 15);
        xsrcb[i] = x + (size_t)(m0 + row) * IN_DIM + gs * 4;
        xdstb[i] = (float*)smem + (wid * 16 + i * 4) * 64;   // wave-uniform
    }
#define DMA_STEP(buf, ks) { _Pragma("unroll") \
    for (int i = 0; i < 4; ++i) dma16(xsrcb[i] + (ks) * 64, xdstb[i] + (buf) * 4096); }

    const bf16_t* w0g = W0t + (size_t)(wid * 64 + l15) * IN_DIM + lg * 8;

    f32x4 acc[4][4] = {};

    DMA_STEP(0, 0);
    __syncthreads();

    #pragma unroll 1
    for (int ks = 0; ks < 8; ++ks) {
        if (ks < 7) DMA_STEP((ks + 1) & 1, ks + 1);
        bf16x8 b0[4], b1[4];
        #pragma unroll
        for (int nr = 0; nr < 4; ++nr) {
            b0[nr] = *(const bf16x8*)(w0g + nr * 16 * IN_DIM + ks * 64);
            b1[nr] = *(const bf16x8*)(w0g + nr * 16 * IN_DIM + ks * 64 + 32);
        }
        const float* xb = (const float*)smem + (ks & 1) * 4096;
        #pragma unroll
        for (int mr = 0; mr < 4; ++mr) {
            bf16x8 a = xfrag(xb, mr * 16 + l15, lg * 2, l15);
            #pragma unroll
            for (int nr = 0; nr < 4; ++nr) acc[mr][nr] = MF(a, b0[nr], acc[mr][nr]);
        }
        #pragma unroll
        for (int mr = 0; mr < 4; ++mr) {
            bf16x8 a = xfrag(xb, mr * 16 + l15, 8 + lg * 2, l15);
            #pragma unroll
            for (int nr = 0; nr < 4; ++nr) acc[mr][nr] = MF(a, b1[nr], acc[mr][nr]);
        }
        __syncthreads();
    }

    // ---------------- P1: BN0 + ReLU -> hs (overwrites xs) ----------------
    {
        bf16_t* hs = (bf16_t*)smem;
        #pragma unroll
        for (int nr = 0; nr < 4; ++nr) {
            int c = wid * 64 + nr * 16 + l15;
            float al = al0[c], be = be0[c];
            #pragma unroll
            for (int mr = 0; mr < 4; ++mr)
                #pragma unroll
                for (int j = 0; j < 4; ++j) {
                    int r = mr * 16 + lg * 4 + j;
                    hs[r * 264 + c] = (bf16_t)fmaxf(acc[mr][nr][j] * al + be, 0.f);
                }
        }
    }
    __syncthreads();

    // ---------------- P2: GEMM1 (64x256x128), A from hs, B L2-direct -------
    {
        const bf16_t* hs  = (const bf16_t*)smem;
        const bf16_t* w1g = W1t + (size_t)(wid * 32 + l15) * H0 + lg * 8;
        f32x4 acc2[4][2] = {};
        #pragma unroll 1
        for (int kf = 0; kf < 8; ++kf) {
            bf16x8 bw0 = *(const bf16x8*)(w1g + kf * 32);
            bf16x8 bw1 = *(const bf16x8*)(w1g + 16 * H0 + kf * 32);
            #pragma unroll
            for (int mr = 0; mr < 4; ++mr) {
                bf16x8 a = *(const bf16x8*)(hs + (mr * 16 + l15) * 264 + kf * 32 + lg * 8);
                acc2[mr][0] = MF(a, bw0, acc2[mr][0]);
                acc2[mr][1] = MF(a, bw1, acc2[mr][1]);
            }
        }
        __syncthreads();     // all hs reads done
        bf16_t* zs = (bf16_t*)smem;  // overwrite hs in place
        #pragma unroll
        for (int nr = 0; nr < 2; ++nr) {
            int c = wid * 32 + nr * 16 + l15;
            float al = al1[c], be = be1[c];
            #pragma unroll
            for (int mr = 0; mr < 4; ++mr)
                #pragma unroll
                for (int j = 0; j < 4; ++j) {
                    int r = mr * 16 + lg * 4 + j;
                    zs[r * 136 + c] = (bf16_t)fmaxf(acc2[mr][nr][j] * al + be, 0.f);
                }
        }
    }
    __syncthreads();         // zs ready

    const bf16_t* zs = (const bf16_t*)smem;
    float* psf  = (float*)(smem + L_PS);
    float* part = (float*)(smem + L_PART);
    const bf16_t* wzg = Wzt + (size_t)(wid * 16 + l15) * H1 + lg * 8;

    // prefetch head A-frags for d=0 (covers P3 latency)
    bf16x8 az0 = *(const bf16x8*)(wzg);
    bf16x8 az1 = *(const bf16x8*)(wzg + 32);
    bf16x8 az2 = *(const bf16x8*)(wzg + 64);
    bf16x8 az3 = *(const bf16x8*)(wzg + 96);

    // ---------------- P3: p = sigmoid(z @ w_init^T) (swapped operands) -----
    {
        f32x4 pacc = {};
        #pragma unroll
        for (int kf = 0; kf < 4; ++kf) {
            bf16x8 aw = *(const bf16x8*)(wiT + l15 * H1 + kf * 32 + lg * 8);
            bf16x8 bz = *(const bf16x8*)(zs + (wid * 16 + l15) * 136 + kf * 32 + lg * 8);
            pacc = MF(aw, bz, pacc);
        }
        #pragma unroll
        for (int j = 0; j < 4; ++j) {
            int d = lg * 4 + j;
            float bi = (d < NDIS) ? b_init[d] : 0.f;
            psf[(wid * 16 + l15) * 17 + d] = 1.f / (1.f + __expf(-(pacc[j] + bi)));
        }
    }
    __syncthreads();         // ps ready

    // ---------------- P4: 12 heads; wave = 16-h slice; 1 barrier/d ---------
    #pragma unroll 1
    for (int d = 0; d < NDIS; ++d) {
        bf16x8 an0 = az0, an1 = az1, an2 = az2, an3 = az3;
        if (d < NDIS - 1) {
            const bf16_t* p = wzg + (size_t)(d + 1) * 8192;
            an0 = *(const bf16x8*)(p);
            an1 = *(const bf16x8*)(p + 32);
            an2 = *(const bf16x8*)(p + 64);
            an3 = *(const bf16x8*)(p + 96);
        }
        f32x4 hacc[4] = {};
        #pragma unroll
        for (int nr = 0; nr < 4; ++nr) {
            const bf16_t* zr = zs + (nr * 16 + l15) * 136 + lg * 8;
            hacc[nr] = MF(az0, *(const bf16x8*)(zr),      hacc[nr]);
            hacc[nr] = MF(az1, *(const bf16x8*)(zr + 32), hacc[nr]);
            hacc[nr] = MF(az2, *(const bf16x8*)(zr + 64), hacc[nr]);
            hacc[nr] = MF(az3, *(const bf16x8*)(zr + 96), hacc[nr]);
        }
        // epilogue: lane holds h = wid*16+lg*4+j (4 h) x r = nr*16+l15 (4 r)
        int i0 = pred_idx[d * 3 + 0], i1 = pred_idx[d * 3 + 1], i2 = pred_idx[d * 3 + 2];
        float wq0 = pred_w[d * 3 + 0], wq1 = pred_w[d * 3 + 1], wq2 = pred_w[d * 3 + 2];
        float bhv[4], wov[4], wpa[4], wpb[4], wpc[4];
        #pragma unroll
        for (int j = 0; j < 4; ++j) {
            int h = wid * 16 + lg * 4 + j;
            bhv[j] = bh[d * 64 + h];
            wov[j] = Wo[d * 64 + h];
            wpa[j] = Wp[d * 192 + h];
            wpb[j] = Wp[d * 192 + 64 + h];
            wpc[j] = Wp[d * 192 + 128 + h];
        }
        #pragma unroll
        for (int nr = 0; nr < 4; ++nr) {
            int r = nr * 16 + l15;
            float a0 = psf[r * 17 + i0] * wq0;
            float a1 = psf[r * 17 + i1] * wq1;
            float a2 = psf[r * 17 + i2] * wq2;
            float s = 0.f;
            #pragma unroll
            for (int j = 0; j < 4; ++j) {
                float v = hacc[nr][j] + bhv[j] + a0 * wpa[j] + a1 * wpb[j] + a2 * wpc[j];
                s += fmaxf(v, 0.f) * wov[j];
            }
            s += __shfl_xor(s, 16);
            s += __shfl_xor(s, 32);
            if (lane < 16) part[(d & 1) * 256 + r * 4 + wid] = s;
        }
        __syncthreads();
        if (tid < 64) {
            f32x4 p4 = *(const f32x4*)(part + (d & 1) * 256 + tid * 4);
            float s = p4[0] + p4[1] + p4[2] + p4[3] + bo[d];
            out[(size_t)(m0 + tid) * NDIS + d] = 1.f / (1.f + __expf(-s));
        }
        az0 = an0; az1 = an1; az2 = an2; az3 = an3;
    }
}

// =====================================================================
extern "C" void kernel_launch(void* const* d_in, const int* in_sizes, int n_in,
                              void* d_out, int out_size, void* d_ws, size_t ws_size,
                              hipStream_t stream) {
    if (ws_size < (size_t)WS_NEED) return;

    const float* x      = (const float*)d_in[0];
    const float* W0     = (const float*)d_in[1];
    const float* b0     = (const float*)d_in[2];
    const float* g0     = (const float*)d_in[3];
    const float* bb0    = (const float*)d_in[4];
    const float* mm0    = (const float*)d_in[5];
    const float* vv0    = (const float*)d_in[6];
    const float* W1     = (const float*)d_in[7];
    const float* b1     = (const float*)d_in[8];
    const float* g1     = (const float*)d_in[9];
    const float* bb1    = (const float*)d_in[10];
    const float* mm1    = (const float*)d_in[11];
    const float* vv1    = (const float*)d_in[12];
    const float* w_init = (const float*)d_in[13];
    const float* b_init = (const float*)d_in[14];
    const float* Wz     = (const float*)d_in[15];
    const float* Wp     = (const float*)d_in[16];
    const float* bh     = (const float*)d_in[17];
    const float* Wo     = (const float*)d_in[18];
    const float* bo     = (const float*)d_in[19];
    const float* pred_w = (const float*)d_in[20];
    const int*   pred_idx = (const int*)d_in[21];

    char* ws = (char*)d_ws;
    const bf16_t* W0t = (const bf16_t*)(ws + WS_W0T);
    const bf16_t* W1t = (const bf16_t*)(ws + WS_W1T);
    const bf16_t* Wzt = (const bf16_t*)(ws + WS_WZT);
    const bf16_t* wiT = (const bf16_t*)(ws + WS_WIT);
    const float* al0 = (const float*)(ws + WS_AL0);
    const float* be0 = (const float*)(ws + WS_BE0);
    const float* al1 = (const float*)(ws + WS_AL1);
    const float* be1 = (const float*)(ws + WS_BE1);

    prep_kernel<<<dim3(512), dim3(256), 0, stream>>>(
        W0, b0, g0, bb0, mm0, vv0, W1, b1, g1, bb1, mm1, vv1, w_init, Wz, ws);

    fused_kernel<<<dim3(B_TOT / 64), dim3(256), 0, stream>>>(
        x, W0t, W1t, al0, be0, al1, be1, Wzt, wiT, b_init, Wp, bh, Wo, bo,
        pred_w, pred_idx, (float*)d_out);
}

// Round 6
// 94.299 us; speedup vs baseline: 2.0275x; 1.0080x over previous
//
#include <hip/hip_runtime.h>
#include <stdint.h>

// Problem constants
#define B_TOT   65536
#define IN_DIM  512
#define H0      256
#define H1      128
#define HH      64
#define NDIS    12

typedef __bf16 bf16_t;
typedef __bf16 bf16x4 __attribute__((ext_vector_type(4)));
typedef __bf16 bf16x8 __attribute__((ext_vector_type(8)));
typedef float  f32x4  __attribute__((ext_vector_type(4)));

// ---- workspace layout (bytes) ----
#define WS_W0T   0u          // bf16 [256][512]  (W0t[c][k] = W0[k][c])
#define WS_W1T   262144u     // bf16 [128][256]
#define WS_WZT   327680u     // bf16 [12][64][128] (Wzt[d][h][e] = Wz[d][e][h])
#define WS_WIT   524288u     // bf16 [16][128]  (w_init rows, zero-padded to 16)
#define WS_AL0   528384u     // f32 [256]
#define WS_BE0   529408u     // f32 [256]
#define WS_AL1   530432u     // f32 [128]
#define WS_BE1   530944u     // f32 [128]
#define WS_NEED  531456u

// ---- fused-kernel LDS (34816 B; 4 blocks/CU) ----
// P0 : x dbuf 2 x [64 rows][8 slots of 16B] bf16 (slot-XOR swizzle)  [0..16384)
// P1/2: hs [64][264] bf16                                            [0..33792)
// P3+ : zs [64][136] bf16 @0 ; ps [64][20] f32 @17408 ;
//       part [12][64][4] f32 @22528 ; obuf (3 KB) aliases ps
#define L_PS     17408u
#define L_PART   22528u
#define L_TOTAL  34816u

__device__ __forceinline__ f32x4 MF(bf16x8 a, bf16x8 b, f32x4 c) {
    return __builtin_amdgcn_mfma_f32_16x16x32_bf16(a, b, c, 0, 0, 0);
}
// Light barrier: LDS-visibility only; does NOT drain vmcnt, so global
// prefetches survive across it (hipcc's __syncthreads drains vmcnt(0)).
__device__ __forceinline__ void BAR() {
    asm volatile("s_waitcnt lgkmcnt(0)\n\ts_barrier" ::: "memory");
}

#define PACK8(o, lo, hi) { o[0]=(bf16_t)lo[0]; o[1]=(bf16_t)lo[1]; o[2]=(bf16_t)lo[2]; o[3]=(bf16_t)lo[3]; \
                           o[4]=(bf16_t)hi[0]; o[5]=(bf16_t)hi[1]; o[6]=(bf16_t)hi[2]; o[7]=(bf16_t)hi[3]; }

// =====================================================================
// Prep: transpose + f32->bf16 weights, fold BN (+bias) into alpha/beta
// =====================================================================
__global__ void prep_kernel(const float* __restrict__ W0, const float* __restrict__ b0,
                            const float* __restrict__ g0, const float* __restrict__ bb0,
                            const float* __restrict__ mm0, const float* __restrict__ vv0,
                            const float* __restrict__ W1, const float* __restrict__ b1,
                            const float* __restrict__ g1, const float* __restrict__ bb1,
                            const float* __restrict__ mm1, const float* __restrict__ vv1,
                            const float* __restrict__ w_init, const float* __restrict__ Wz,
                            char* __restrict__ ws)
{
    bf16_t* W0t = (bf16_t*)(ws + WS_W0T);
    bf16_t* W1t = (bf16_t*)(ws + WS_W1T);
    bf16_t* Wzt = (bf16_t*)(ws + WS_WZT);
    bf16_t* wiT = (bf16_t*)(ws + WS_WIT);
    float* al0 = (float*)(ws + WS_AL0);
    float* be0 = (float*)(ws + WS_BE0);
    float* al1 = (float*)(ws + WS_AL1);
    float* be1 = (float*)(ws + WS_BE1);

    int t = blockIdx.x * 256 + threadIdx.x;   // 512*256 = 131072 threads

    { // W0t: 256*512
        int c = t >> 9, k = t & 511;
        W0t[t] = (bf16_t)W0[k * H0 + c];
    }
    if (t < H1 * H0) { // W1t
        int c = t >> 8, k = t & 255;
        W1t[t] = (bf16_t)W1[k * H1 + c];
    }
    if (t < NDIS * HH * H1) { // Wzt ; Wz is [12][128][64]
        int d = t >> 13, r = t & 8191, h = r >> 7, e = r & 127;
        Wzt[t] = (bf16_t)Wz[d * 8192 + e * 64 + h];
    }
    if (t < 16 * H1) { // w_initT (pad 12->16)
        int d = t >> 7, e = t & 127;
        wiT[t] = (d < NDIS) ? (bf16_t)w_init[d * H1 + e] : (bf16_t)0.0f;
    }
    if (t < H0) {
        float a = g0[t] * rsqrtf(vv0[t] + 1e-5f);
        al0[t] = a;
        be0[t] = (b0[t] - mm0[t]) * a + bb0[t];
    }
    if (t < H1) {
        float a = g1[t] * rsqrtf(vv1[t] + 1e-5f);
        al1[t] = a;
        be1[t] = (b1[t] - mm1[t]) * a + bb1[t];
    }
}

// =====================================================================
// Fused kernel: 64 rows/block, 256 threads (4 waves).
// Swapped MFMA operands everywhere: A = weight rows, B = activation rows,
// so D comes out column-grouped in the output-feature dim (vector epilogues).
// =====================================================================
__global__ __launch_bounds__(256, 4) void fused_kernel(
    const float* __restrict__ x,
    const bf16_t* __restrict__ W0t, const bf16_t* __restrict__ W1t,
    const float* __restrict__ al0, const float* __restrict__ be0,
    const float* __restrict__ al1, const float* __restrict__ be1,
    const bf16_t* __restrict__ Wzt, const bf16_t* __restrict__ wiT,
    const float* __restrict__ b_init, const float* __restrict__ Wp,
    const float* __restrict__ bh, const float* __restrict__ Wo,
    const float* __restrict__ bo, const float* __restrict__ pred_w,
    const int* __restrict__ pred_idx, float* __restrict__ out)
{
    __shared__ __align__(16) char smem[L_TOTAL];

    const int tid  = threadIdx.x;
    const int lane = tid & 63, wid = tid >> 6;
    const int l15 = lane & 15, lg = lane >> 4;
    const int m0 = blockIdx.x * 64;

    bf16_t* xs = (bf16_t*)smem;

    // ---- P0: GEMM0 (h^T = W0t @ x-rows), BK=64, 8 steps, bf16 x-staging ---
    // staging map: 2 (row,slot) pairs per thread; slot = 16B = 8 k-values
    const float *sgp0, *sgp1;
    int sd0, sd1;
    {
        int f0 = tid, f1 = tid + 256;
        int r0 = f0 >> 3, s0 = f0 & 7, r1 = f1 >> 3, s1 = f1 & 7;
        sgp0 = x + (size_t)(m0 + r0) * IN_DIM + s0 * 8;
        sgp1 = x + (size_t)(m0 + r1) * IN_DIM + s1 * 8;
        sd0 = r0 * 64 + ((s0 ^ (r0 & 7)) << 3);
        sd1 = r1 * 64 + ((s1 ^ (r1 & 7)) << 3);
    }
    const bf16_t* wg = W0t + (size_t)(wid * 64 + l15) * IN_DIM + lg * 8;
    const int xb0 = ((lg ^ (l15 & 7)) << 3);         // kf=0 chunk
    const int xb1 = (((4 | lg) ^ (l15 & 7)) << 3);   // kf=1 chunk
    const int xrow = l15 * 64;

    f32x4 acc[4][4] = {};    // [mf(h-col)][nf(batch-row)]
    f32x4 lo0, hi0, lo1, hi1;

    // prologue: stage step0, prefetch step1
    lo0 = *(const f32x4*)(sgp0);     hi0 = *(const f32x4*)(sgp0 + 4);
    lo1 = *(const f32x4*)(sgp1);     hi1 = *(const f32x4*)(sgp1 + 4);
    { bf16x8 o; PACK8(o, lo0, hi0); *(bf16x8*)(xs + sd0) = o; }
    { bf16x8 o; PACK8(o, lo1, hi1); *(bf16x8*)(xs + sd1) = o; }
    lo0 = *(const f32x4*)(sgp0 + 64); hi0 = *(const f32x4*)(sgp0 + 68);
    lo1 = *(const f32x4*)(sgp1 + 64); hi1 = *(const f32x4*)(sgp1 + 68);
    BAR();

    #pragma unroll 1
    for (int ks = 0; ks < 8; ++ks) {
        // A-frags (W0t, L2-resident) for this step
        bf16x8 a0[4], a1[4];
        #pragma unroll
        for (int mf = 0; mf < 4; ++mf) {
            a0[mf] = *(const bf16x8*)(wg + mf * 16 * IN_DIM + ks * 64);
            a1[mf] = *(const bf16x8*)(wg + mf * 16 * IN_DIM + ks * 64 + 32);
        }
        // stage x(ks+1) into the other buffer; prefetch x(ks+2)
        if (ks < 7) {
            bf16_t* xw = xs + ((ks + 1) & 1) * 4096;
            { bf16x8 o; PACK8(o, lo0, hi0); *(bf16x8*)(xw + sd0) = o; }
            { bf16x8 o; PACK8(o, lo1, hi1); *(bf16x8*)(xw + sd1) = o; }
            if (ks < 6) {
                lo0 = *(const f32x4*)(sgp0 + (ks + 2) * 64); hi0 = *(const f32x4*)(sgp0 + (ks + 2) * 64 + 4);
                lo1 = *(const f32x4*)(sgp1 + (ks + 2) * 64); hi1 = *(const f32x4*)(sgp1 + (ks + 2) * 64 + 4);
            }
        }
        // MFMA from buffer ks&1
        const bf16_t* xr = xs + (ks & 1) * 4096;
        #pragma unroll
        for (int nf = 0; nf < 4; ++nf) {
            bf16x8 b = *(const bf16x8*)(xr + nf * 1024 + xrow + xb0);
            #pragma unroll
            for (int mf = 0; mf < 4; ++mf) acc[mf][nf] = MF(a0[mf], b, acc[mf][nf]);
        }
        #pragma unroll
        for (int nf = 0; nf < 4; ++nf) {
            bf16x8 b = *(const bf16x8*)(xr + nf * 1024 + xrow + xb1);
            #pragma unroll
            for (int mf = 0; mf < 4; ++mf) acc[mf][nf] = MF(a1[mf], b, acc[mf][nf]);
        }
        BAR();
    }

    // ---- P1: BN0 + ReLU -> hs [64][264] (vector bf16x4 writes) ----
    {
        bf16_t* hs = (bf16_t*)smem;
        #pragma unroll
        for (int mf = 0; mf < 4; ++mf) {
            int c = wid * 64 + mf * 16 + lg * 4;
            f32x4 al = *(const f32x4*)(al0 + c);
            f32x4 be = *(const f32x4*)(be0 + c);
            #pragma unroll
            for (int nf = 0; nf < 4; ++nf) {
                int r = nf * 16 + l15;
                bf16x4 o;
                #pragma unroll
                for (int j = 0; j < 4; ++j)
                    o[j] = (bf16_t)fmaxf(acc[mf][nf][j] * al[j] + be[j], 0.f);
                *(bf16x4*)(hs + r * 264 + c) = o;
            }
        }
    }
    BAR();

    // ---- P2: GEMM1 (z^T = W1t @ h-rows), A 2-ahead from L2, B from hs ----
    f32x4 acc2[2][4] = {};
    {
        const bf16_t* hs  = (const bf16_t*)smem;
        const bf16_t* w1g = W1t + (size_t)(wid * 32 + l15) * H0 + lg * 8;
        bf16x8 aP[2], aQ[2];
        aP[0] = *(const bf16x8*)(w1g);
        aP[1] = *(const bf16x8*)(w1g + 16 * H0);
        aQ[0] = *(const bf16x8*)(w1g + 32);
        aQ[1] = *(const bf16x8*)(w1g + 16 * H0 + 32);
        #pragma unroll
        for (int kf = 0; kf < 8; ++kf) {
            bf16x8 ac0 = (kf & 1) ? aQ[0] : aP[0];
            bf16x8 ac1 = (kf & 1) ? aQ[1] : aP[1];
            if (kf < 6) {
                if (kf & 1) {
                    aQ[0] = *(const bf16x8*)(w1g + (kf + 2) * 32);
                    aQ[1] = *(const bf16x8*)(w1g + 16 * H0 + (kf + 2) * 32);
                } else {
                    aP[0] = *(const bf16x8*)(w1g + (kf + 2) * 32);
                    aP[1] = *(const bf16x8*)(w1g + 16 * H0 + (kf + 2) * 32);
                }
            }
            #pragma unroll
            for (int nf = 0; nf < 4; ++nf) {
                bf16x8 b = *(const bf16x8*)(hs + (nf * 16 + l15) * 264 + kf * 32 + lg * 8);
                acc2[0][nf] = MF(ac0, b, acc2[0][nf]);
                acc2[1][nf] = MF(ac1, b, acc2[1][nf]);
            }
        }
    }
    BAR();   // all hs reads complete block-wide
    {
        bf16_t* zs = (bf16_t*)smem;   // overwrite hs region
        #pragma unroll
        for (int mf = 0; mf < 2; ++mf) {
            int c = wid * 32 + mf * 16 + lg * 4;
            f32x4 al = *(const f32x4*)(al1 + c);
            f32x4 be = *(const f32x4*)(be1 + c);
            #pragma unroll
            for (int nf = 0; nf < 4; ++nf) {
                int r = nf * 16 + l15;
                bf16x4 o;
                #pragma unroll
                for (int j = 0; j < 4; ++j)
                    o[j] = (bf16_t)fmaxf(acc2[mf][nf][j] * al[j] + be[j], 0.f);
                *(bf16x4*)(zs + r * 136 + c) = o;
            }
        }
    }
    BAR();

    const bf16_t* zs = (const bf16_t*)smem;
    float* psf  = (float*)(smem + L_PS);     // [64][20] f32
    float* part = (float*)(smem + L_PART);   // [12][64][4] f32
    const bf16_t* wzg = Wzt + (size_t)(wid * 16 + l15) * H1 + lg * 8;

    // prefetch d=0 head A-frags (covers P3 latency)
    bf16x8 az0 = *(const bf16x8*)(wzg);
    bf16x8 az1 = *(const bf16x8*)(wzg + 32);
    bf16x8 az2 = *(const bf16x8*)(wzg + 64);
    bf16x8 az3 = *(const bf16x8*)(wzg + 96);

    // ---- P3: p = sigmoid(z @ w_init^T)  (A = wiT rows, B = wave's z rows) --
    {
        f32x4 pacc = {};
        #pragma unroll
        for (int kf = 0; kf < 4; ++kf) {
            bf16x8 aw = *(const bf16x8*)(wiT + l15 * H1 + kf * 32 + lg * 8);
            bf16x8 bz = *(const bf16x8*)(zs + (wid * 16 + l15) * 136 + kf * 32 + lg * 8);
            pacc = MF(aw, bz, pacc);
        }
        f32x4 pv;
        #pragma unroll
        for (int j = 0; j < 4; ++j) {
            int d = lg * 4 + j;
            float bi = (d < NDIS) ? b_init[d] : 0.f;
            pv[j] = 1.f / (1.f + __expf(-(pacc[j] + bi)));
        }
        *(f32x4*)(psf + (wid * 16 + l15) * 20 + lg * 4) = pv;
    }
    BAR();

    // ---- P4: 12 heads, ZERO barriers in loop; partials to LDS ----
    #pragma unroll 1
    for (int d = 0; d < NDIS; ++d) {
        bf16x8 an0 = az0, an1 = az1, an2 = az2, an3 = az3;
        if (d < NDIS - 1) {
            const bf16_t* p = wzg + (size_t)(d + 1) * 8192;
            an0 = *(const bf16x8*)(p);      an1 = *(const bf16x8*)(p + 32);
            an2 = *(const bf16x8*)(p + 64); an3 = *(const bf16x8*)(p + 96);
        }
        int i0 = pred_idx[d * 3 + 0], i1 = pred_idx[d * 3 + 1], i2 = pred_idx[d * 3 + 2];
        float wq0 = pred_w[d * 3 + 0], wq1 = pred_w[d * 3 + 1], wq2 = pred_w[d * 3 + 2];
        int hb = wid * 16 + lg * 4;
        f32x4 bhv = *(const f32x4*)(bh + d * 64 + hb);
        f32x4 wov = *(const f32x4*)(Wo + d * 64 + hb);
        f32x4 wpa = *(const f32x4*)(Wp + d * 192 + hb);
        f32x4 wpb = *(const f32x4*)(Wp + d * 192 + 64 + hb);
        f32x4 wpc = *(const f32x4*)(Wp + d * 192 + 128 + hb);

        #pragma unroll
        for (int nf = 0; nf < 4; ++nf) {
            const bf16_t* zr = zs + (nf * 16 + l15) * 136 + lg * 8;
            f32x4 hacc = {};
            hacc = MF(az0, *(const bf16x8*)(zr),      hacc);
            hacc = MF(az1, *(const bf16x8*)(zr + 32), hacc);
            hacc = MF(az2, *(const bf16x8*)(zr + 64), hacc);
            hacc = MF(az3, *(const bf16x8*)(zr + 96), hacc);
            int r = nf * 16 + l15;
            float a0 = psf[r * 20 + i0] * wq0;
            float a1 = psf[r * 20 + i1] * wq1;
            float a2 = psf[r * 20 + i2] * wq2;
            float s = 0.f;
            #pragma unroll
            for (int j = 0; j < 4; ++j) {
                float v = hacc[j] + bhv[j] + a0 * wpa[j] + a1 * wpb[j] + a2 * wpc[j];
                s += fmaxf(v, 0.f) * wov[j];
            }
            s += __shfl_xor(s, 16);
            s += __shfl_xor(s, 32);
            if (lane < 16) part[d * 256 + r * 4 + wid] = s;
        }
        az0 = an0; az1 = an1; az2 = an2; az3 = an3;
    }
    BAR();

    // ---- final: reduce part, sigmoid, coalesced store ----
    {
        float* obuf = (float*)(smem + L_PS);   // aliases ps (dead)
        #pragma unroll
        for (int i = 0; i < 3; ++i) {
            int e = tid * 3 + i;
            int d = e % 12, r = e / 12;
            f32x4 p = *(const f32x4*)(part + d * 256 + r * 4);
            float s = p[0] + p[1] + p[2] + p[3] + bo[d];
            obuf[e] = 1.f / (1.f + __expf(-s));
        }
    }
    BAR();
    if (tid < 192) {
        f32x4 o = *(const f32x4*)((const float*)(smem + L_PS) + tid * 4);
        *(f32x4*)(out + (size_t)blockIdx.x * 768 + tid * 4) = o;
    }
}

// =====================================================================
extern "C" void kernel_launch(void* const* d_in, const int* in_sizes, int n_in,
                              void* d_out, int out_size, void* d_ws, size_t ws_size,
                              hipStream_t stream) {
    if (ws_size < (size_t)WS_NEED) return;

    const float* x      = (const float*)d_in[0];
    const float* W0     = (const float*)d_in[1];
    const float* b0     = (const float*)d_in[2];
    const float* g0     = (const float*)d_in[3];
    const float* bb0    = (const float*)d_in[4];
    const float* mm0    = (const float*)d_in[5];
    const float* vv0    = (const float*)d_in[6];
    const float* W1     = (const float*)d_in[7];
    const float* b1     = (const float*)d_in[8];
    const float* g1     = (const float*)d_in[9];
    const float* bb1    = (const float*)d_in[10];
    const float* mm1    = (const float*)d_in[11];
    const float* vv1    = (const float*)d_in[12];
    const float* w_init = (const float*)d_in[13];
    const float* b_init = (const float*)d_in[14];
    const float* Wz     = (const float*)d_in[15];
    const float* Wp     = (const float*)d_in[16];
    const float* bh     = (const float*)d_in[17];
    const float* Wo     = (const float*)d_in[18];
    const float* bo     = (const float*)d_in[19];
    const float* pred_w = (const float*)d_in[20];
    const int*   pred_idx = (const int*)d_in[21];

    char* ws = (char*)d_ws;
    const bf16_t* W0t = (const bf16_t*)(ws + WS_W0T);
    const bf16_t* W1t = (const bf16_t*)(ws + WS_W1T);
    const bf16_t* Wzt = (const bf16_t*)(ws + WS_WZT);
    const bf16_t* wiT = (const bf16_t*)(ws + WS_WIT);
    const float* al0 = (const float*)(ws + WS_AL0);
    const float* be0 = (const float*)(ws + WS_BE0);
    const float* al1 = (const float*)(ws + WS_AL1);
    const float* be1 = (const float*)(ws + WS_BE1);

    prep_kernel<<<dim3(512), dim3(256), 0, stream>>>(
        W0, b0, g0, bb0, mm0, vv0, W1, b1, g1, bb1, mm1, vv1, w_init, Wz, ws);

    fused_kernel<<<dim3(B_TOT / 64), dim3(256), 0, stream>>>(
        x, W0t, W1t, al0, be0, al1, be1, Wzt, wiT, b_init, Wp, bh, Wo, bo,
        pred_w, pred_idx, (float*)d_out);
}